// Round 1
// baseline (25.634 us; speedup 1.0000x reference)
//
#include <hip/hip_runtime.h>
#include <math.h>

#define EPSC 1.1920928955078125e-07f
#define BATCH 8388608
#define NBCE_BLOCKS 1024
#define IN_FEATS 2048
#define ROW_CHUNKS 16
#define ROWS_PER_CHUNK 64

__global__ __launch_bounds__(256) void bce_partial_k(const float* __restrict__ p,
                                                     const float* __restrict__ y,
                                                     float* __restrict__ partial) {
    const float4* p4 = (const float4*)p;
    const float4* y4 = (const float4*)y;
    const int tid = blockIdx.x * blockDim.x + threadIdx.x;
    const int nthreads = gridDim.x * blockDim.x;   // 262144
    float acc = 0.0f;
    for (int i = tid; i < BATCH / 4; i += nthreads) {
        float4 pv = p4[i];
        float4 yv = y4[i];
        float pp[4] = {pv.x, pv.y, pv.z, pv.w};
        float yy[4] = {yv.x, yv.y, yv.z, yv.w};
        #pragma unroll
        for (int k = 0; k < 4; ++k) {
            float pc  = fminf(fmaxf(pp[k],        EPSC), 1.0f - EPSC);
            float pmc = fminf(fmaxf(1.0f - pp[k], EPSC), 1.0f - EPSC);
            float lp  = __logf(pc);
            float l1  = __logf(pmc);
            // nll = -(0.7*y*log_p + 0.3*(1-y)*log_1mp)
            acc -= 0.7f * yy[k] * lp + 0.3f * (1.0f - yy[k]) * l1;
        }
    }
    __shared__ float s[256];
    s[threadIdx.x] = acc;
    __syncthreads();
    #pragma unroll
    for (int o = 128; o > 0; o >>= 1) {
        if (threadIdx.x < o) s[threadIdx.x] += s[threadIdx.x + o];
        __syncthreads();
    }
    if (threadIdx.x == 0) partial[blockIdx.x] = s[0];
}

__global__ __launch_bounds__(256) void colsq_partial_k(const float* __restrict__ W,
                                                       float* __restrict__ part) {
    const int col   = blockIdx.x * 256 + threadIdx.x;  // 0..2047 (gridDim.x = 8)
    const int chunk = blockIdx.y;                      // 0..15
    const float* base = W + (size_t)chunk * ROWS_PER_CHUNK * IN_FEATS + col;
    float acc = 0.0f;
    #pragma unroll 8
    for (int r = 0; r < ROWS_PER_CHUNK; ++r) {
        float w = base[(size_t)r * IN_FEATS];
        acc = fmaf(w, w, acc);
    }
    part[chunk * IN_FEATS + col] = acc;
}

__device__ __forceinline__ float penalty_f(float x) {
    return 1.0f - __expf(-x * x) + fabsf(x);
}

__global__ __launch_bounds__(1024) void finalize_k(const float* __restrict__ bce_part,
                                                   const float* __restrict__ colsq_part,
                                                   float* __restrict__ out) {
    __shared__ float cn[IN_FEATS];
    const int t = threadIdx.x;
    // reduce row-chunk partials -> column norms
    for (int c = t; c < IN_FEATS; c += 1024) {
        float s = 0.0f;
        #pragma unroll
        for (int k = 0; k < ROW_CHUNKS; ++k) s += colsq_part[k * IN_FEATS + c];
        cn[c] = sqrtf(s);
    }
    __syncthreads();

    float reg = 0.0f;
    // tail columns 1024..2047: f(col_norm)
    {
        float x = cn[1024 + t];
        reg += penalty_f(x);
    }
    // groups: 64 groups of 16 over first 1024 columns
    if (t < 64) {
        float gs = 0.0f;
        #pragma unroll
        for (int k = 0; k < 16; ++k) gs += cn[t * 16 + k];
        reg += penalty_f(gs * (1.0f / 16.0f));
    }
    float bce = bce_part[t];   // exactly 1024 partials, one per thread

    __shared__ float sr[1024];
    __shared__ float sb[1024];
    sr[t] = reg;
    sb[t] = bce;
    __syncthreads();
    #pragma unroll
    for (int o = 512; o > 0; o >>= 1) {
        if (t < o) { sr[t] += sr[t + o]; sb[t] += sb[t + o]; }
        __syncthreads();
    }
    if (t == 0) {
        out[0] = sb[0] * (1.0f / (float)BATCH) + 0.01f * sr[0];
    }
}

extern "C" void kernel_launch(void* const* d_in, const int* in_sizes, int n_in,
                              void* d_out, int out_size, void* d_ws, size_t ws_size,
                              hipStream_t stream) {
    const float* p = (const float*)d_in[0];
    const float* y = (const float*)d_in[1];
    const float* W = (const float*)d_in[2];
    float* out = (float*)d_out;

    float* bce_part   = (float*)d_ws;            // 1024 floats
    float* colsq_part = bce_part + NBCE_BLOCKS;  // 16*2048 floats

    bce_partial_k<<<NBCE_BLOCKS, 256, 0, stream>>>(p, y, bce_part);
    colsq_partial_k<<<dim3(8, ROW_CHUNKS), 256, 0, stream>>>(W, colsq_part);
    finalize_k<<<1, 1024, 0, stream>>>(bce_part, colsq_part, out);
}